// Round 6
// baseline (434.286 us; speedup 1.0000x reference)
//
#include <hip/hip_runtime.h>
#include <stdint.h>

// QuantizedLinear (BitNet ternary): out = x @ q^T + bias
// x: [8192, 4096] fp32, weight: [4096, 4096] fp32 ([out,in]), bias: [4096] fp32
// gamma = mean(|W|) + 1e-5 ; q = clip(rint(W/gamma), -1, 1)
// Strategy: quantize to ternary bf16, convert x to bf16, run bf16 MFMA GEMM
// (m97-style 128x128 tile, BK=64, global_load_lds width-16 staging).

#define M_DIM 8192
#define N_DIM 4096
#define K_DIM 4096
#define BM 128
#define BN 128
#define BK 64

typedef __attribute__((ext_vector_type(8))) short bf16x8;
typedef __attribute__((ext_vector_type(4))) float f32x4;

// ---------- helpers ----------
__device__ __forceinline__ unsigned short f2bf_rne(float f) {
  unsigned int u = __float_as_uint(f);
  unsigned int r = (u + 0x7FFFu + ((u >> 16) & 1u)) >> 16;
  return (unsigned short)r;
}

__device__ __forceinline__ void load_lds16(const void* g, void* l) {
  __builtin_amdgcn_global_load_lds(
      (const __attribute__((address_space(1))) void*)g,
      (__attribute__((address_space(3))) void*)l,
      16, 0, 0);
}

// ---------- K1: per-block partial sums of |w| (deterministic) ----------
__global__ __launch_bounds__(256) void k_abs_partial(const float* __restrict__ w,
                                                     double* __restrict__ partial) {
  const int tid = threadIdx.x;
  const size_t base = (size_t)blockIdx.x * 8192 + (size_t)tid * 4;
  double s = 0.0;
#pragma unroll
  for (int it = 0; it < 8; ++it) {
    const float4 v = *reinterpret_cast<const float4*>(w + base + (size_t)it * 1024);
    s += (double)fabsf(v.x) + (double)fabsf(v.y) + (double)fabsf(v.z) + (double)fabsf(v.w);
  }
  __shared__ double sd[256];
  sd[tid] = s;
  __syncthreads();
  for (int off = 128; off > 0; off >>= 1) {
    if (tid < off) sd[tid] += sd[tid + off];
    __syncthreads();
  }
  if (tid == 0) partial[blockIdx.x] = sd[0];
}

// ---------- K2: finalize gamma (fp32 like numpy) ----------
__global__ __launch_bounds__(256) void k_abs_final(const double* __restrict__ partial,
                                                   float* __restrict__ gamma_out) {
  const int tid = threadIdx.x;
  double s = 0.0;
  for (int i = tid; i < 2048; i += 256) s += partial[i];
  __shared__ double sd[256];
  sd[tid] = s;
  __syncthreads();
  for (int off = 128; off > 0; off >>= 1) {
    if (tid < off) sd[tid] += sd[tid + off];
    __syncthreads();
  }
  if (tid == 0) {
    float g = (float)(sd[0] / 16777216.0);  // mean over 4096*4096
    gamma_out[0] = g + 1e-5f;
  }
}

// ---------- K3: quantize W -> ternary bf16 bits ----------
__global__ __launch_bounds__(256) void k_quant(const float* __restrict__ w,
                                               const float* __restrict__ gamma_p,
                                               unsigned short* __restrict__ qb) {
  const float g = gamma_p[0];
  const size_t n4 = (size_t)N_DIM * K_DIM / 4;
  const size_t stride = (size_t)gridDim.x * blockDim.x;
  for (size_t i = (size_t)blockIdx.x * blockDim.x + threadIdx.x; i < n4; i += stride) {
    const float4 v = reinterpret_cast<const float4*>(w)[i];
    ushort4 o;
    float r;
    r = rintf(v.x / g); o.x = (r >= 1.0f) ? 0x3F80 : ((r <= -1.0f) ? 0xBF80 : 0);
    r = rintf(v.y / g); o.y = (r >= 1.0f) ? 0x3F80 : ((r <= -1.0f) ? 0xBF80 : 0);
    r = rintf(v.z / g); o.z = (r >= 1.0f) ? 0x3F80 : ((r <= -1.0f) ? 0xBF80 : 0);
    r = rintf(v.w / g); o.w = (r >= 1.0f) ? 0x3F80 : ((r <= -1.0f) ? 0xBF80 : 0);
    reinterpret_cast<ushort4*>(qb)[i] = o;
  }
}

// ---------- K4: x fp32 -> bf16 ----------
__global__ __launch_bounds__(256) void k_cvt_x(const float* __restrict__ x,
                                               unsigned short* __restrict__ xb) {
  const size_t n4 = (size_t)M_DIM * K_DIM / 4;
  const size_t stride = (size_t)gridDim.x * blockDim.x;
  for (size_t i = (size_t)blockIdx.x * blockDim.x + threadIdx.x; i < n4; i += stride) {
    const float4 v = reinterpret_cast<const float4*>(x)[i];
    ushort4 o;
    o.x = f2bf_rne(v.x);
    o.y = f2bf_rne(v.y);
    o.z = f2bf_rne(v.z);
    o.w = f2bf_rne(v.w);
    reinterpret_cast<ushort4*>(xb)[i] = o;
  }
}

// ---------- K5: bf16 MFMA GEMM, C = A[M,K] * B[N,K]^T + bias ----------
__global__ __launch_bounds__(256) void k_gemm(const unsigned short* __restrict__ A,
                                              const unsigned short* __restrict__ B,
                                              const float* __restrict__ bias,
                                              float* __restrict__ C) {
  __shared__ unsigned short As[BM][BK];  // 16 KB
  __shared__ unsigned short Bs[BN][BK];  // 16 KB

  const int tid = threadIdx.x;
  const int wid = tid >> 6;
  const int lane = tid & 63;
  const int wr = wid >> 1;   // wave row (0..1)
  const int wc = wid & 1;    // wave col (0..1)
  const int l15 = lane & 15;
  const int l4 = lane >> 4;  // 0..3

  const int brow = blockIdx.y * BM;
  const int bcol = blockIdx.x * BN;
  const size_t a_base = (size_t)brow * K_DIM;
  const size_t b_base = (size_t)bcol * K_DIM;

  f32x4 acc[4][4];
#pragma unroll
  for (int i = 0; i < 4; ++i)
#pragma unroll
    for (int j = 0; j < 4; ++j)
#pragma unroll
      for (int e = 0; e < 4; ++e) acc[i][j][e] = 0.0f;

  for (int kt = 0; kt < K_DIM / BK; ++kt) {
    const int k0 = kt * BK;
    // stage A and B tiles: 1024 16B segments each, 4 issues per thread each
#pragma unroll
    for (int i = 0; i < 4; ++i) {
      const int s = i * 256 + tid;       // 0..1023
      const int row = s >> 3;            // 0..127
      const int cg = (s & 7) * 8;        // col start (elements)
      const int wave_seg = i * 256 + wid * 64;  // wave-uniform
      load_lds16(A + a_base + (size_t)row * K_DIM + (k0 + cg),
                 (char*)&As[0][0] + (size_t)wave_seg * 16);
      load_lds16(B + b_base + (size_t)row * K_DIM + (k0 + cg),
                 (char*)&Bs[0][0] + (size_t)wave_seg * 16);
    }
    __syncthreads();  // drains vmcnt; tiles ready
#pragma unroll
    for (int kk = 0; kk < 2; ++kk) {
      bf16x8 af[4], bfr[4];
#pragma unroll
      for (int mi = 0; mi < 4; ++mi)
        af[mi] = *reinterpret_cast<const bf16x8*>(&As[wr * 64 + mi * 16 + l15][kk * 32 + l4 * 8]);
#pragma unroll
      for (int ni = 0; ni < 4; ++ni)
        bfr[ni] = *reinterpret_cast<const bf16x8*>(&Bs[wc * 64 + ni * 16 + l15][kk * 32 + l4 * 8]);
#pragma unroll
      for (int mi = 0; mi < 4; ++mi)
#pragma unroll
        for (int ni = 0; ni < 4; ++ni)
          acc[mi][ni] = __builtin_amdgcn_mfma_f32_16x16x32_bf16(af[mi], bfr[ni], acc[mi][ni], 0, 0, 0);
    }
    __syncthreads();  // all reads done before next stage overwrites
  }

  // epilogue: C/D layout col=lane&15, row=(lane>>4)*4+j
  float bi[4];
#pragma unroll
  for (int ni = 0; ni < 4; ++ni) bi[ni] = bias[bcol + wc * 64 + ni * 16 + l15];
#pragma unroll
  for (int mi = 0; mi < 4; ++mi) {
#pragma unroll
    for (int j = 0; j < 4; ++j) {
      const int row = brow + wr * 64 + mi * 16 + l4 * 4 + j;
      float* crow = C + (size_t)row * N_DIM + bcol + wc * 64 + l15;
#pragma unroll
      for (int ni = 0; ni < 4; ++ni) crow[ni * 16] = acc[mi][ni][j] + bi[ni];
    }
  }
}

extern "C" void kernel_launch(void* const* d_in, const int* in_sizes, int n_in,
                              void* d_out, int out_size, void* d_ws, size_t ws_size,
                              hipStream_t stream) {
  (void)in_sizes; (void)n_in; (void)out_size; (void)ws_size;
  const float* x = (const float*)d_in[0];
  const float* w = (const float*)d_in[1];
  const float* bias = (const float*)d_in[2];
  float* out = (float*)d_out;

  char* ws = (char*)d_ws;
  unsigned short* xb = (unsigned short*)ws;                                  // 64 MB
  unsigned short* qb = (unsigned short*)(ws + (size_t)M_DIM * K_DIM * 2);    // 32 MB
  double* partial = (double*)(ws + (size_t)M_DIM * K_DIM * 2 + (size_t)N_DIM * K_DIM * 2);
  float* gamma = (float*)(partial + 2048);

  k_abs_partial<<<2048, 256, 0, stream>>>(w, partial);
  k_abs_final<<<1, 256, 0, stream>>>(partial, gamma);
  k_quant<<<2048, 256, 0, stream>>>(w, gamma, qb);
  k_cvt_x<<<2048, 256, 0, stream>>>(x, xb);

  dim3 grid(N_DIM / BN, M_DIM / BM);
  k_gemm<<<grid, 256, 0, stream>>>(xb, qb, bias, out);
}

// Round 9
// 366.591 us; speedup vs baseline: 1.1847x; 1.1847x over previous
//
#include <hip/hip_runtime.h>
#include <stdint.h>

// QuantizedLinear (BitNet ternary): out = x @ q^T + bias
// bf16 MFMA GEMM (m97-style 128x128 tile, BK=64) + T2 both-sides XOR swizzle:
// LDS dest linear (global_load_lds requirement), global SOURCE pre-inverse-
// swizzled, ds_read swizzled (rule #21). Kills the 16-way 128B-stride bank
// conflict (measured 1.0e8 conflict cycles, ~37% of kernel time in R6).

#define M_DIM 8192
#define N_DIM 4096
#define K_DIM 4096
#define BM 128
#define BN 128
#define BK 64

typedef __attribute__((ext_vector_type(8))) short bf16x8;
typedef __attribute__((ext_vector_type(4))) float f32x4;

// ---------- helpers ----------
__device__ __forceinline__ unsigned short f2bf_rne(float f) {
  unsigned int u = __float_as_uint(f);
  unsigned int r = (u + 0x7FFFu + ((u >> 16) & 1u)) >> 16;
  return (unsigned short)r;
}

__device__ __forceinline__ void load_lds16(const void* g, void* l) {
  __builtin_amdgcn_global_load_lds(
      (const __attribute__((address_space(1))) void*)g,
      (__attribute__((address_space(3))) void*)l,
      16, 0, 0);
}

// ---------- K1: per-block partial sums of |w| (deterministic) ----------
__global__ __launch_bounds__(256) void k_abs_partial(const float* __restrict__ w,
                                                     double* __restrict__ partial) {
  const int tid = threadIdx.x;
  const size_t base = (size_t)blockIdx.x * 8192 + (size_t)tid * 4;
  double s = 0.0;
#pragma unroll
  for (int it = 0; it < 8; ++it) {
    const float4 v = *reinterpret_cast<const float4*>(w + base + (size_t)it * 1024);
    s += (double)fabsf(v.x) + (double)fabsf(v.y) + (double)fabsf(v.z) + (double)fabsf(v.w);
  }
  __shared__ double sd[256];
  sd[tid] = s;
  __syncthreads();
  for (int off = 128; off > 0; off >>= 1) {
    if (tid < off) sd[tid] += sd[tid + off];
    __syncthreads();
  }
  if (tid == 0) partial[blockIdx.x] = sd[0];
}

// ---------- K2: finalize gamma (fp32 like numpy) ----------
__global__ __launch_bounds__(256) void k_abs_final(const double* __restrict__ partial,
                                                   float* __restrict__ gamma_out) {
  const int tid = threadIdx.x;
  double s = 0.0;
  for (int i = tid; i < 2048; i += 256) s += partial[i];
  __shared__ double sd[256];
  sd[tid] = s;
  __syncthreads();
  for (int off = 128; off > 0; off >>= 1) {
    if (tid < off) sd[tid] += sd[tid + off];
    __syncthreads();
  }
  if (tid == 0) {
    float g = (float)(sd[0] / 16777216.0);  // mean over 4096*4096
    gamma_out[0] = g + 1e-5f;
  }
}

// ---------- K3: quantize W -> ternary bf16 bits ----------
__global__ __launch_bounds__(256) void k_quant(const float* __restrict__ w,
                                               const float* __restrict__ gamma_p,
                                               unsigned short* __restrict__ qb) {
  const float g = gamma_p[0];
  const size_t n4 = (size_t)N_DIM * K_DIM / 4;
  const size_t stride = (size_t)gridDim.x * blockDim.x;
  for (size_t i = (size_t)blockIdx.x * blockDim.x + threadIdx.x; i < n4; i += stride) {
    const float4 v = reinterpret_cast<const float4*>(w)[i];
    ushort4 o;
    float r;
    r = rintf(v.x / g); o.x = (r >= 1.0f) ? 0x3F80 : ((r <= -1.0f) ? 0xBF80 : 0);
    r = rintf(v.y / g); o.y = (r >= 1.0f) ? 0x3F80 : ((r <= -1.0f) ? 0xBF80 : 0);
    r = rintf(v.z / g); o.z = (r >= 1.0f) ? 0x3F80 : ((r <= -1.0f) ? 0xBF80 : 0);
    r = rintf(v.w / g); o.w = (r >= 1.0f) ? 0x3F80 : ((r <= -1.0f) ? 0xBF80 : 0);
    reinterpret_cast<ushort4*>(qb)[i] = o;
  }
}

// ---------- K4: x fp32 -> bf16 ----------
__global__ __launch_bounds__(256) void k_cvt_x(const float* __restrict__ x,
                                               unsigned short* __restrict__ xb) {
  const size_t n4 = (size_t)M_DIM * K_DIM / 4;
  const size_t stride = (size_t)gridDim.x * blockDim.x;
  for (size_t i = (size_t)blockIdx.x * blockDim.x + threadIdx.x; i < n4; i += stride) {
    const float4 v = reinterpret_cast<const float4*>(x)[i];
    ushort4 o;
    o.x = f2bf_rne(v.x);
    o.y = f2bf_rne(v.y);
    o.z = f2bf_rne(v.z);
    o.w = f2bf_rne(v.w);
    reinterpret_cast<ushort4*>(xb)[i] = o;
  }
}

// ---------- K5: bf16 MFMA GEMM, C = A[M,K] * B[N,K]^T + bias ----------
// LDS swizzle: logical tile byte (row, cb) stored at physical byte
// row*128 + (cb ^ ((row&7)<<4)). Involution; 16B-granular; bijective per row.
__global__ __launch_bounds__(256) void k_gemm(const unsigned short* __restrict__ A,
                                              const unsigned short* __restrict__ B,
                                              const float* __restrict__ bias,
                                              float* __restrict__ C) {
  __shared__ unsigned short As[BM][BK];  // 16 KB, stored swizzled
  __shared__ unsigned short Bs[BN][BK];  // 16 KB, stored swizzled

  const int tid = threadIdx.x;
  const int wid = tid >> 6;
  const int lane = tid & 63;
  const int wr = wid >> 1;   // wave row (0..1)
  const int wc = wid & 1;    // wave col (0..1)
  const int l15 = lane & 15;
  const int l4 = lane >> 4;  // 0..3
  const int xorv = (l15 & 7) << 4;  // read-side swizzle (bytes); row%8 == l15%8

  const int brow = blockIdx.y * BM;
  const int bcol = blockIdx.x * BN;
  const size_t a_base = (size_t)brow * K_DIM;
  const size_t b_base = (size_t)bcol * K_DIM;

  f32x4 acc[4][4];
#pragma unroll
  for (int i = 0; i < 4; ++i)
#pragma unroll
    for (int j = 0; j < 4; ++j)
#pragma unroll
      for (int e = 0; e < 4; ++e) acc[i][j][e] = 0.0f;

  for (int kt = 0; kt < K_DIM / BK; ++kt) {
    const int k0 = kt * BK;
    // stage A and B tiles: linear LDS dest, inverse-swizzled global source.
    // thread's 16B goes to linear LDS byte s*16 = row*128 + (s&7)*16, which
    // must hold logical column bytes ((s&7)*16) ^ ((row&7)<<4).
#pragma unroll
    for (int i = 0; i < 4; ++i) {
      const int s = i * 256 + tid;       // 0..1023
      const int row = s >> 3;            // 0..127
      const int cg = (((s & 7) * 16) ^ ((row & 7) << 4)) >> 1;  // element col
      const int wave_seg = i * 256 + wid * 64;  // wave-uniform
      load_lds16(A + a_base + (size_t)row * K_DIM + (k0 + cg),
                 (char*)&As[0][0] + (size_t)wave_seg * 16);
      load_lds16(B + b_base + (size_t)row * K_DIM + (k0 + cg),
                 (char*)&Bs[0][0] + (size_t)wave_seg * 16);
    }
    __syncthreads();  // drains vmcnt; tiles ready
#pragma unroll
    for (int kk = 0; kk < 2; ++kk) {
      // logical col byte = kk*64 + l4*16; physical = ^ xorv (bits 4-6 only)
      const int ce = ((kk * 64 + l4 * 16) ^ xorv) >> 1;  // element offset in row
      bf16x8 af[4], bfr[4];
#pragma unroll
      for (int mi = 0; mi < 4; ++mi)
        af[mi] = *reinterpret_cast<const bf16x8*>(
            &As[0][0] + (wr * 64 + mi * 16 + l15) * BK + ce);
#pragma unroll
      for (int ni = 0; ni < 4; ++ni)
        bfr[ni] = *reinterpret_cast<const bf16x8*>(
            &Bs[0][0] + (wc * 64 + ni * 16 + l15) * BK + ce);
#pragma unroll
      for (int mi = 0; mi < 4; ++mi)
#pragma unroll
        for (int ni = 0; ni < 4; ++ni)
          acc[mi][ni] = __builtin_amdgcn_mfma_f32_16x16x32_bf16(af[mi], bfr[ni], acc[mi][ni], 0, 0, 0);
    }
    __syncthreads();  // all reads done before next stage overwrites
  }

  // epilogue: C/D layout col=lane&15, row=(lane>>4)*4+j
  float bi[4];
#pragma unroll
  for (int ni = 0; ni < 4; ++ni) bi[ni] = bias[bcol + wc * 64 + ni * 16 + l15];
#pragma unroll
  for (int mi = 0; mi < 4; ++mi) {
#pragma unroll
    for (int j = 0; j < 4; ++j) {
      const int row = brow + wr * 64 + mi * 16 + l4 * 4 + j;
      float* crow = C + (size_t)row * N_DIM + bcol + wc * 64 + l15;
#pragma unroll
      for (int ni = 0; ni < 4; ++ni) crow[ni * 16] = acc[mi][ni][j] + bi[ni];
    }
  }
}

extern "C" void kernel_launch(void* const* d_in, const int* in_sizes, int n_in,
                              void* d_out, int out_size, void* d_ws, size_t ws_size,
                              hipStream_t stream) {
  (void)in_sizes; (void)n_in; (void)out_size; (void)ws_size;
  const float* x = (const float*)d_in[0];
  const float* w = (const float*)d_in[1];
  const float* bias = (const float*)d_in[2];
  float* out = (float*)d_out;

  char* ws = (char*)d_ws;
  unsigned short* xb = (unsigned short*)ws;                                  // 64 MB
  unsigned short* qb = (unsigned short*)(ws + (size_t)M_DIM * K_DIM * 2);    // 32 MB
  double* partial = (double*)(ws + (size_t)M_DIM * K_DIM * 2 + (size_t)N_DIM * K_DIM * 2);
  float* gamma = (float*)(partial + 2048);

  k_abs_partial<<<2048, 256, 0, stream>>>(w, partial);
  k_abs_final<<<1, 256, 0, stream>>>(partial, gamma);
  k_quant<<<2048, 256, 0, stream>>>(w, gamma, qb);
  k_cvt_x<<<2048, 256, 0, stream>>>(x, xb);

  dim3 grid(N_DIM / BN, M_DIM / BM);
  k_gemm<<<grid, 256, 0, stream>>>(xb, qb, bias, out);
}

// Round 10
// 289.663 us; speedup vs baseline: 1.4993x; 1.2656x over previous
//
#include <hip/hip_runtime.h>
#include <stdint.h>

// QuantizedLinear (BitNet ternary): out = x @ q^T + bias
// 256x256 8-phase bf16 MFMA GEMM (T2 swizzle + T3/T4 counted-vmcnt + T5 setprio).
// 8 waves (2M x 4N), BK=64, 128KiB dbuf LDS, staging order [A0,A1,B0,B1],
// waits: vmcnt(4) mid-tile, vmcnt(2) at boundary, vmcnt(0) only before tail tile.

#define M_DIM 8192
#define N_DIM 4096
#define K_DIM 4096
#define BM 256
#define BN 256
#define BK 64

typedef __attribute__((ext_vector_type(8))) short bf16x8;
typedef __attribute__((ext_vector_type(4))) float f32x4;

#define BAR() asm volatile("s_barrier" ::: "memory")
#define VMW(n) asm volatile("s_waitcnt vmcnt(" #n ")" ::: "memory")
#define LGK0()                                  \
  do {                                          \
    asm volatile("s_waitcnt lgkmcnt(0)" ::: "memory"); \
    __builtin_amdgcn_sched_barrier(0);          \
  } while (0)

// ---------- helpers ----------
__device__ __forceinline__ unsigned short f2bf_rne(float f) {
  unsigned int u = __float_as_uint(f);
  unsigned int r = (u + 0x7FFFu + ((u >> 16) & 1u)) >> 16;
  return (unsigned short)r;
}

__device__ __forceinline__ void load_lds16(const void* g, void* l) {
  __builtin_amdgcn_global_load_lds(
      (const __attribute__((address_space(1))) void*)g,
      (__attribute__((address_space(3))) void*)l,
      16, 0, 0);
}

// ---------- K1: per-block partial sums of |w| (deterministic) ----------
__global__ __launch_bounds__(256) void k_abs_partial(const float* __restrict__ w,
                                                     double* __restrict__ partial) {
  const int tid = threadIdx.x;
  const size_t base = (size_t)blockIdx.x * 8192 + (size_t)tid * 4;
  double s = 0.0;
#pragma unroll
  for (int it = 0; it < 8; ++it) {
    const float4 v = *reinterpret_cast<const float4*>(w + base + (size_t)it * 1024);
    s += (double)fabsf(v.x) + (double)fabsf(v.y) + (double)fabsf(v.z) + (double)fabsf(v.w);
  }
  __shared__ double sd[256];
  sd[tid] = s;
  __syncthreads();
  for (int off = 128; off > 0; off >>= 1) {
    if (tid < off) sd[tid] += sd[tid + off];
    __syncthreads();
  }
  if (tid == 0) partial[blockIdx.x] = sd[0];
}

// ---------- K2: finalize gamma (fp32 like numpy) ----------
__global__ __launch_bounds__(256) void k_abs_final(const double* __restrict__ partial,
                                                   float* __restrict__ gamma_out) {
  const int tid = threadIdx.x;
  double s = 0.0;
  for (int i = tid; i < 2048; i += 256) s += partial[i];
  __shared__ double sd[256];
  sd[tid] = s;
  __syncthreads();
  for (int off = 128; off > 0; off >>= 1) {
    if (tid < off) sd[tid] += sd[tid + off];
    __syncthreads();
  }
  if (tid == 0) {
    float g = (float)(sd[0] / 16777216.0);  // mean over 4096*4096
    gamma_out[0] = g + 1e-5f;
  }
}

// ---------- K3: quantize W -> ternary bf16 bits ----------
__global__ __launch_bounds__(256) void k_quant(const float* __restrict__ w,
                                               const float* __restrict__ gamma_p,
                                               unsigned short* __restrict__ qb) {
  const float g = gamma_p[0];
  const size_t n4 = (size_t)N_DIM * K_DIM / 4;
  const size_t stride = (size_t)gridDim.x * blockDim.x;
  for (size_t i = (size_t)blockIdx.x * blockDim.x + threadIdx.x; i < n4; i += stride) {
    const float4 v = reinterpret_cast<const float4*>(w)[i];
    ushort4 o;
    float r;
    r = rintf(v.x / g); o.x = (r >= 1.0f) ? 0x3F80 : ((r <= -1.0f) ? 0xBF80 : 0);
    r = rintf(v.y / g); o.y = (r >= 1.0f) ? 0x3F80 : ((r <= -1.0f) ? 0xBF80 : 0);
    r = rintf(v.z / g); o.z = (r >= 1.0f) ? 0x3F80 : ((r <= -1.0f) ? 0xBF80 : 0);
    r = rintf(v.w / g); o.w = (r >= 1.0f) ? 0x3F80 : ((r <= -1.0f) ? 0xBF80 : 0);
    reinterpret_cast<ushort4*>(qb)[i] = o;
  }
}

// ---------- K4: x fp32 -> bf16 ----------
__global__ __launch_bounds__(256) void k_cvt_x(const float* __restrict__ x,
                                               unsigned short* __restrict__ xb) {
  const size_t n4 = (size_t)M_DIM * K_DIM / 4;
  const size_t stride = (size_t)gridDim.x * blockDim.x;
  for (size_t i = (size_t)blockIdx.x * blockDim.x + threadIdx.x; i < n4; i += stride) {
    const float4 v = reinterpret_cast<const float4*>(x)[i];
    ushort4 o;
    o.x = f2bf_rne(v.x);
    o.y = f2bf_rne(v.y);
    o.z = f2bf_rne(v.z);
    o.w = f2bf_rne(v.w);
    reinterpret_cast<ushort4*>(xb)[i] = o;
  }
}

// ---------- K5: 256x256 8-phase bf16 MFMA GEMM ----------
// LDS swizzle (verified R9, 0 conflicts): logical (row, cb) at physical byte
// row*128 + (cb ^ ((row&7)<<4)); realized as inverse-swizzled global source
// (linear glds dest) + swizzled ds_read offset.
__global__ __launch_bounds__(512, 2) void k_gemm(const unsigned short* __restrict__ A,
                                                 const unsigned short* __restrict__ B,
                                                 const float* __restrict__ bias,
                                                 float* __restrict__ C) {
  __shared__ unsigned short lds[2][2][256][64];  // 128 KiB: [buf][op A=0/B=1][row][col]

  const int tid = threadIdx.x;
  const int wid = tid >> 6;   // 0..7
  const int lane = tid & 63;
  const int wm = wid >> 2;    // 0..1  (A row-half of this wave)
  const int wn = wid & 3;     // 0..3  (interleaved 16-col strip)
  const int l15 = lane & 15;
  const int l4 = lane >> 4;   // 0..3

  const int brow = blockIdx.y * BM;
  const int bcol = blockIdx.x * BN;

  // staging constants: seg s covers (row = s>>3, 16B slot = s&7) of a 128-row half
  const int s1 = 512 + tid;
  const int r0row = tid >> 3, r1row = s1 >> 3;
  const int r0col = ((((tid & 7) << 4) ^ ((r0row & 7) << 4)) >> 1);
  const int r1col = ((((s1 & 7) << 4) ^ ((r1row & 7) << 4)) >> 1);

  // ds_read swizzled column offsets (elements) for k-step 0/1
  const int xorv = (l15 & 7) << 4;
  const int ce0 = ((l4 * 16) ^ xorv) >> 1;
  const int ce1 = ((64 + l4 * 16) ^ xorv) >> 1;

#define STAGE(buf, op, half, kt)                                                      \
  do {                                                                                \
    const unsigned short* g0 =                                                        \
        ((op) ? B + (size_t)(bcol + (half)*128 + r0row) * K_DIM                       \
              : A + (size_t)(brow + (half)*128 + r0row) * K_DIM) + (kt)*64 + r0col;   \
    load_lds16(g0, (char*)&lds[buf][op][(half)*128][0] + (size_t)(wid * 64) * 16);    \
    const unsigned short* g1 =                                                        \
        ((op) ? B + (size_t)(bcol + (half)*128 + r1row) * K_DIM                       \
              : A + (size_t)(brow + (half)*128 + r1row) * K_DIM) + (kt)*64 + r1col;   \
    load_lds16(g1, (char*)&lds[buf][op][(half)*128][0] + (size_t)(512 + wid * 64) * 16); \
  } while (0)

#define LDA(i, k) (*reinterpret_cast<const bf16x8*>(                                   \
    &lds[cur][0][0][0] + (size_t)(wm * 128 + (i)*16 + l15) * 64 + ((k) ? ce1 : ce0)))
#define LDB(p, k) (*reinterpret_cast<const bf16x8*>(                                   \
    &lds[cur][1][0][0] + (size_t)((p)*64 + wn * 16 + l15) * 64 + ((k) ? ce1 : ce0)))

#define MFMA16(P)                                                                      \
  do {                                                                                 \
    __builtin_amdgcn_s_setprio(1);                                                     \
    _Pragma("unroll") for (int i = 0; i < 8; ++i) {                                    \
      acc[i][P] = __builtin_amdgcn_mfma_f32_16x16x32_bf16(a[i][0], b[0], acc[i][P], 0, 0, 0); \
      acc[i][P] = __builtin_amdgcn_mfma_f32_16x16x32_bf16(a[i][1], b[1], acc[i][P], 0, 0, 0); \
    }                                                                                  \
    __builtin_amdgcn_s_setprio(0);                                                     \
  } while (0)

  f32x4 acc[8][4];
#pragma unroll
  for (int i = 0; i < 8; ++i)
#pragma unroll
    for (int p = 0; p < 4; ++p)
#pragma unroll
      for (int e = 0; e < 4; ++e) acc[i][p][e] = 0.0f;

  // prologue: stage tile 0 fully into buf 0 (order = consumption order)
  STAGE(0, 0, 0, 0);
  STAGE(0, 0, 1, 0);
  STAGE(0, 1, 0, 0);
  STAGE(0, 1, 1, 0);
  VMW(2);  // A0,A1,B0 landed; B1 may fly until mid-tile wait
  BAR();

  bf16x8 a[8][2], b[2];
  int cur = 0;

  for (int t = 0; t < 63; ++t) {
    const int nbuf = cur ^ 1;
    const int nxt = t + 1;
    // ---- phase 0: n=0 (needs A-all + B rows 0..63) ----
#pragma unroll
    for (int i = 0; i < 8; ++i) { a[i][0] = LDA(i, 0); a[i][1] = LDA(i, 1); }
    b[0] = LDB(0, 0); b[1] = LDB(0, 1);
    STAGE(nbuf, 0, 0, nxt);
    BAR(); LGK0();
    MFMA16(0);
    BAR();
    // ---- phase 1: n=1 (B rows 64..127, still B-half0) ----
    b[0] = LDB(1, 0); b[1] = LDB(1, 1);
    STAGE(nbuf, 0, 1, nxt);
    BAR(); LGK0();
    MFMA16(1);
    VMW(4);  // publish B-half1 of tile t (oldest 2 of 6 outstanding)
    BAR();
    // ---- phase 2: n=2 (B rows 128..191, B-half1) ----
    b[0] = LDB(2, 0); b[1] = LDB(2, 1);
    STAGE(nbuf, 1, 0, nxt);
    BAR(); LGK0();
    MFMA16(2);
    BAR();
    // ---- phase 3: n=3 (B rows 192..255) ----
    b[0] = LDB(3, 0); b[1] = LDB(3, 1);
    STAGE(nbuf, 1, 1, nxt);
    BAR(); LGK0();
    MFMA16(3);
    VMW(2);  // publish next tile's A0,A1,B0 (only its B1 may fly)
    BAR();
    cur = nbuf;
  }

  // ---- tail tile 63 (no staging; drain everything) ----
  VMW(0);
  BAR();
#pragma unroll
  for (int i = 0; i < 8; ++i) { a[i][0] = LDA(i, 0); a[i][1] = LDA(i, 1); }
  bf16x8 bb[4][2];
#pragma unroll
  for (int p = 0; p < 4; ++p) { bb[p][0] = LDB(p, 0); bb[p][1] = LDB(p, 1); }
  __builtin_amdgcn_s_setprio(1);
#pragma unroll
  for (int i = 0; i < 8; ++i)
#pragma unroll
    for (int p = 0; p < 4; ++p) {
      acc[i][p] = __builtin_amdgcn_mfma_f32_16x16x32_bf16(a[i][0], bb[p][0], acc[i][p], 0, 0, 0);
      acc[i][p] = __builtin_amdgcn_mfma_f32_16x16x32_bf16(a[i][1], bb[p][1], acc[i][p], 0, 0, 0);
    }
  __builtin_amdgcn_s_setprio(0);

  // ---- epilogue: C/D layout col=lane&15, row=(lane>>4)*4+j ----
  float bi[4];
#pragma unroll
  for (int p = 0; p < 4; ++p) bi[p] = bias[bcol + p * 64 + wn * 16 + l15];
#pragma unroll
  for (int i = 0; i < 8; ++i) {
#pragma unroll
    for (int j = 0; j < 4; ++j) {
      const int row = brow + wm * 128 + i * 16 + l4 * 4 + j;
      float* crow = C + (size_t)row * N_DIM + bcol + wn * 16 + l15;
#pragma unroll
      for (int p = 0; p < 4; ++p) crow[p * 64] = acc[i][p][j] + bi[p];
    }
  }
#undef STAGE
#undef LDA
#undef LDB
#undef MFMA16
}

extern "C" void kernel_launch(void* const* d_in, const int* in_sizes, int n_in,
                              void* d_out, int out_size, void* d_ws, size_t ws_size,
                              hipStream_t stream) {
  (void)in_sizes; (void)n_in; (void)out_size; (void)ws_size;
  const float* x = (const float*)d_in[0];
  const float* w = (const float*)d_in[1];
  const float* bias = (const float*)d_in[2];
  float* out = (float*)d_out;

  char* ws = (char*)d_ws;
  unsigned short* xb = (unsigned short*)ws;                                  // 64 MB
  unsigned short* qb = (unsigned short*)(ws + (size_t)M_DIM * K_DIM * 2);    // 32 MB
  double* partial = (double*)(ws + (size_t)M_DIM * K_DIM * 2 + (size_t)N_DIM * K_DIM * 2);
  float* gamma = (float*)(partial + 2048);

  k_abs_partial<<<2048, 256, 0, stream>>>(w, partial);
  k_abs_final<<<1, 256, 0, stream>>>(partial, gamma);
  k_quant<<<2048, 256, 0, stream>>>(w, gamma, qb);
  k_cvt_x<<<2048, 256, 0, stream>>>(x, xb);

  dim3 grid(N_DIM / BN, M_DIM / BM);
  k_gemm<<<grid, 512, 0, stream>>>(xb, qb, bias, out);
}

// Round 11
// 275.084 us; speedup vs baseline: 1.5787x; 1.0530x over previous
//
#include <hip/hip_runtime.h>
#include <stdint.h>

// QuantizedLinear (BitNet ternary): out = x @ q^T + bias
// 256x256 bf16 MFMA GEMM, 8 waves (2M x 4N), BK=64, 128KiB dbuf LDS,
// T2 both-sides XOR swizzle (0 conflicts, R9) + within-tile READ-AHEAD:
// issue 24 ds_reads (2 batches of 12) + 8 glds up front, lgkmcnt(12) -> Q0
// overlaps batch-2 LDS service, lgkmcnt(0) -> Q1/Q2/Q3. 1 barrier/K-tile.

#define M_DIM 8192
#define N_DIM 4096
#define K_DIM 4096
#define BM 256
#define BN 256
#define BK 64

typedef __attribute__((ext_vector_type(8))) short bf16x8;
typedef __attribute__((ext_vector_type(4))) float f32x4;

#define BAR() asm volatile("s_barrier" ::: "memory")
#define VMW0() asm volatile("s_waitcnt vmcnt(0)" ::: "memory")
#define SB0() __builtin_amdgcn_sched_barrier(0)
#define LGKM(n)                                             \
  do {                                                      \
    SB0();                                                  \
    asm volatile("s_waitcnt lgkmcnt(" #n ")" ::: "memory"); \
    SB0();                                                  \
  } while (0)
#define MFMA_(d, va, vb) \
  d = __builtin_amdgcn_mfma_f32_16x16x32_bf16(va, vb, d, 0, 0, 0)

// ---------- helpers ----------
__device__ __forceinline__ unsigned short f2bf_rne(float f) {
  unsigned int u = __float_as_uint(f);
  unsigned int r = (u + 0x7FFFu + ((u >> 16) & 1u)) >> 16;
  return (unsigned short)r;
}

__device__ __forceinline__ void load_lds16(const void* g, void* l) {
  __builtin_amdgcn_global_load_lds(
      (const __attribute__((address_space(1))) void*)g,
      (__attribute__((address_space(3))) void*)l,
      16, 0, 0);
}

// ---------- K1: per-block partial sums of |w| (deterministic) ----------
__global__ __launch_bounds__(256) void k_abs_partial(const float* __restrict__ w,
                                                     double* __restrict__ partial) {
  const int tid = threadIdx.x;
  const size_t base = (size_t)blockIdx.x * 8192 + (size_t)tid * 4;
  double s = 0.0;
#pragma unroll
  for (int it = 0; it < 8; ++it) {
    const float4 v = *reinterpret_cast<const float4*>(w + base + (size_t)it * 1024);
    s += (double)fabsf(v.x) + (double)fabsf(v.y) + (double)fabsf(v.z) + (double)fabsf(v.w);
  }
  __shared__ double sd[256];
  sd[tid] = s;
  __syncthreads();
  for (int off = 128; off > 0; off >>= 1) {
    if (tid < off) sd[tid] += sd[tid + off];
    __syncthreads();
  }
  if (tid == 0) partial[blockIdx.x] = sd[0];
}

// ---------- K2: finalize gamma (fp32 like numpy) ----------
__global__ __launch_bounds__(256) void k_abs_final(const double* __restrict__ partial,
                                                   float* __restrict__ gamma_out) {
  const int tid = threadIdx.x;
  double s = 0.0;
  for (int i = tid; i < 2048; i += 256) s += partial[i];
  __shared__ double sd[256];
  sd[tid] = s;
  __syncthreads();
  for (int off = 128; off > 0; off >>= 1) {
    if (tid < off) sd[tid] += sd[tid + off];
    __syncthreads();
  }
  if (tid == 0) {
    float g = (float)(sd[0] / 16777216.0);  // mean over 4096*4096
    gamma_out[0] = g + 1e-5f;
  }
}

// ---------- K3: quantize W -> ternary bf16 bits ----------
__global__ __launch_bounds__(256) void k_quant(const float* __restrict__ w,
                                               const float* __restrict__ gamma_p,
                                               unsigned short* __restrict__ qb) {
  const float g = gamma_p[0];
  const size_t n4 = (size_t)N_DIM * K_DIM / 4;
  const size_t stride = (size_t)gridDim.x * blockDim.x;
  for (size_t i = (size_t)blockIdx.x * blockDim.x + threadIdx.x; i < n4; i += stride) {
    const float4 v = reinterpret_cast<const float4*>(w)[i];
    ushort4 o;
    float r;
    r = rintf(v.x / g); o.x = (r >= 1.0f) ? 0x3F80 : ((r <= -1.0f) ? 0xBF80 : 0);
    r = rintf(v.y / g); o.y = (r >= 1.0f) ? 0x3F80 : ((r <= -1.0f) ? 0xBF80 : 0);
    r = rintf(v.z / g); o.z = (r >= 1.0f) ? 0x3F80 : ((r <= -1.0f) ? 0xBF80 : 0);
    r = rintf(v.w / g); o.w = (r >= 1.0f) ? 0x3F80 : ((r <= -1.0f) ? 0xBF80 : 0);
    reinterpret_cast<ushort4*>(qb)[i] = o;
  }
}

// ---------- K4: x fp32 -> bf16 ----------
__global__ __launch_bounds__(256) void k_cvt_x(const float* __restrict__ x,
                                               unsigned short* __restrict__ xb) {
  const size_t n4 = (size_t)M_DIM * K_DIM / 4;
  const size_t stride = (size_t)gridDim.x * blockDim.x;
  for (size_t i = (size_t)blockIdx.x * blockDim.x + threadIdx.x; i < n4; i += stride) {
    const float4 v = reinterpret_cast<const float4*>(x)[i];
    ushort4 o;
    o.x = f2bf_rne(v.x);
    o.y = f2bf_rne(v.y);
    o.z = f2bf_rne(v.z);
    o.w = f2bf_rne(v.w);
    reinterpret_cast<ushort4*>(xb)[i] = o;
  }
}

// ---------- K5: 256x256 read-ahead bf16 MFMA GEMM ----------
// LDS swizzle (verified R9/R10, 0 conflicts): logical (row, cb) at physical
// byte row*128 + (cb ^ ((row&7)<<4)); inverse-swizzled global source
// (linear glds dest) + swizzled ds_read offset.
__global__ __launch_bounds__(512, 2) void k_gemm(const unsigned short* __restrict__ A,
                                                 const unsigned short* __restrict__ B,
                                                 const float* __restrict__ bias,
                                                 float* __restrict__ C) {
  __shared__ unsigned short lds[2][2][256][64];  // 128 KiB: [buf][op A=0/B=1][row][col]

  const int tid = threadIdx.x;
  const int wid = tid >> 6;   // 0..7
  const int lane = tid & 63;
  const int wm = wid >> 2;    // 0..1  (A row-half of this wave)
  const int wn = wid & 3;     // 0..3  (interleaved 16-col strip)
  const int l15 = lane & 15;
  const int l4 = lane >> 4;   // 0..3

  const int brow = blockIdx.y * BM;
  const int bcol = blockIdx.x * BN;

  // staging constants: seg s covers (row = s>>3, 16B slot = s&7) of a 128-row half
  const int s1 = 512 + tid;
  const int r0row = tid >> 3, r1row = s1 >> 3;
  const int r0col = ((((tid & 7) << 4) ^ ((r0row & 7) << 4)) >> 1);
  const int r1col = ((((s1 & 7) << 4) ^ ((r1row & 7) << 4)) >> 1);

  // ds_read swizzled column offsets (elements) for k-step 0/1
  const int xorv = (l15 & 7) << 4;
  const int ce0 = ((l4 * 16) ^ xorv) >> 1;
  const int ce1 = ((64 + l4 * 16) ^ xorv) >> 1;

#define STAGE(buf, op, half, kt)                                                      \
  do {                                                                                \
    const unsigned short* g0 =                                                        \
        ((op) ? B + (size_t)(bcol + (half)*128 + r0row) * K_DIM                       \
              : A + (size_t)(brow + (half)*128 + r0row) * K_DIM) + (kt)*64 + r0col;   \
    load_lds16(g0, (char*)&lds[buf][op][(half)*128][0] + (size_t)(wid * 64) * 16);    \
    const unsigned short* g1 =                                                        \
        ((op) ? B + (size_t)(bcol + (half)*128 + r1row) * K_DIM                       \
              : A + (size_t)(brow + (half)*128 + r1row) * K_DIM) + (kt)*64 + r1col;   \
    load_lds16(g1, (char*)&lds[buf][op][(half)*128][0] + (size_t)(512 + wid * 64) * 16); \
  } while (0)

#define LDA(i, k) (*reinterpret_cast<const bf16x8*>(                                   \
    &lds[cur][0][0][0] + (size_t)(wm * 128 + (i)*16 + l15) * 64 + ((k) ? ce1 : ce0)))
#define LDB(p, k) (*reinterpret_cast<const bf16x8*>(                                   \
    &lds[cur][1][0][0] + (size_t)((p)*64 + wn * 16 + l15) * 64 + ((k) ? ce1 : ce0)))

  // batch 1: aL (4i x 2k = 8) + bL (2p x 2k = 4) = 12 ds_read_b128
#define READ_BATCH1()                                                   \
  do {                                                                  \
    _Pragma("unroll") for (int i = 0; i < 4; ++i) {                     \
      aL[i][0] = LDA(i, 0); aL[i][1] = LDA(i, 1);                       \
    }                                                                   \
    bL[0][0] = LDB(0, 0); bL[0][1] = LDB(0, 1);                         \
    bL[1][0] = LDB(1, 0); bL[1][1] = LDB(1, 1);                         \
  } while (0)
  // batch 2: aH (8) + bH (4) = 12 ds_read_b128
#define READ_BATCH2()                                                   \
  do {                                                                  \
    _Pragma("unroll") for (int i = 0; i < 4; ++i) {                     \
      aH[i][0] = LDA(i + 4, 0); aH[i][1] = LDA(i + 4, 1);               \
    }                                                                   \
    bH[0][0] = LDB(2, 0); bH[0][1] = LDB(2, 1);                         \
    bH[1][0] = LDB(3, 0); bH[1][1] = LDB(3, 1);                         \
  } while (0)
  // quadrants: Q0 = aL x bL -> acc[0..3][0..1]; Q1 = aH x bH -> acc[4..7][2..3];
  //            Q2 = aL x bH -> acc[0..3][2..3]; Q3 = aH x bL -> acc[4..7][0..1]
#define MFMAQ(AV, BV, IO, PO)                                           \
  do {                                                                  \
    _Pragma("unroll") for (int i = 0; i < 4; ++i)                       \
      _Pragma("unroll") for (int p = 0; p < 2; ++p) {                   \
        MFMA_(acc[(IO) + i][(PO) + p], AV[i][0], BV[p][0]);             \
        MFMA_(acc[(IO) + i][(PO) + p], AV[i][1], BV[p][1]);             \
      }                                                                 \
  } while (0)

  f32x4 acc[8][4];
#pragma unroll
  for (int i = 0; i < 8; ++i)
#pragma unroll
    for (int p = 0; p < 4; ++p)
#pragma unroll
      for (int e = 0; e < 4; ++e) acc[i][p][e] = 0.0f;

  // prologue: stage tile 0 fully into buf 0
  STAGE(0, 0, 0, 0);
  STAGE(0, 0, 1, 0);
  STAGE(0, 1, 0, 0);
  STAGE(0, 1, 1, 0);
  VMW0();
  BAR();

  bf16x8 aL[4][2], aH[4][2], bL[2][2], bH[2][2];
  int cur = 0;

  for (int t = 0; t < 63; ++t) {
    const int nbuf = cur ^ 1;
    const int nxt = t + 1;
    // issue batch 1, staging, batch 2 -- all before any wait
    READ_BATCH1();
    SB0();
    STAGE(nbuf, 0, 0, nxt);
    STAGE(nbuf, 0, 1, nxt);
    STAGE(nbuf, 1, 0, nxt);
    STAGE(nbuf, 1, 1, nxt);
    SB0();
    READ_BATCH2();
    LGKM(12);  // batch 1 landed; batch 2 still in flight under Q0
    __builtin_amdgcn_s_setprio(1);
    MFMAQ(aL, bL, 0, 0);  // Q0
    LGKM(0);   // batch 2 landed
    MFMAQ(aH, bH, 4, 2);  // Q1
    MFMAQ(aL, bH, 0, 2);  // Q2
    MFMAQ(aH, bL, 4, 0);  // Q3
    __builtin_amdgcn_s_setprio(0);
    VMW0();    // staging issued ~a full tile ago; latency long covered
    BAR();     // publish buf[nbuf] to all waves
    cur = nbuf;
  }

  // ---- tail tile 63 (no staging) ----
  READ_BATCH1();
  SB0();
  READ_BATCH2();
  LGKM(12);
  __builtin_amdgcn_s_setprio(1);
  MFMAQ(aL, bL, 0, 0);
  LGKM(0);
  MFMAQ(aH, bH, 4, 2);
  MFMAQ(aL, bH, 0, 2);
  MFMAQ(aH, bL, 4, 0);
  __builtin_amdgcn_s_setprio(0);

  // ---- epilogue: C/D layout col=lane&15, row=(lane>>4)*4+j ----
  float bi[4];
#pragma unroll
  for (int p = 0; p < 4; ++p) bi[p] = bias[bcol + p * 64 + wn * 16 + l15];
#pragma unroll
  for (int i = 0; i < 8; ++i) {
#pragma unroll
    for (int j = 0; j < 4; ++j) {
      const int row = brow + wm * 128 + i * 16 + l4 * 4 + j;
      float* crow = C + (size_t)row * N_DIM + bcol + wn * 16 + l15;
#pragma unroll
      for (int p = 0; p < 4; ++p) crow[p * 64] = acc[i][p][j] + bi[p];
    }
  }
#undef STAGE
#undef LDA
#undef LDB
#undef READ_BATCH1
#undef READ_BATCH2
#undef MFMAQ
}

extern "C" void kernel_launch(void* const* d_in, const int* in_sizes, int n_in,
                              void* d_out, int out_size, void* d_ws, size_t ws_size,
                              hipStream_t stream) {
  (void)in_sizes; (void)n_in; (void)out_size; (void)ws_size;
  const float* x = (const float*)d_in[0];
  const float* w = (const float*)d_in[1];
  const float* bias = (const float*)d_in[2];
  float* out = (float*)d_out;

  char* ws = (char*)d_ws;
  unsigned short* xb = (unsigned short*)ws;                                  // 64 MB
  unsigned short* qb = (unsigned short*)(ws + (size_t)M_DIM * K_DIM * 2);    // 32 MB
  double* partial = (double*)(ws + (size_t)M_DIM * K_DIM * 2 + (size_t)N_DIM * K_DIM * 2);
  float* gamma = (float*)(partial + 2048);

  k_abs_partial<<<2048, 256, 0, stream>>>(w, partial);
  k_abs_final<<<1, 256, 0, stream>>>(partial, gamma);
  k_quant<<<2048, 256, 0, stream>>>(w, gamma, qb);
  k_cvt_x<<<2048, 256, 0, stream>>>(x, xb);

  dim3 grid(N_DIM / BN, M_DIM / BM);
  k_gemm<<<grid, 512, 0, stream>>>(xb, qb, bias, out);
}